// Round 7
// baseline (163.839 us; speedup 1.0000x reference)
//
#include <hip/hip_runtime.h>
#include <math.h>

#define EPS 1e-6f
#define C 1604
#define B 16384
#define C4 401                    // C/4 exact
#define ROWS_PER_WAVE 2
#define WAVES_PER_BLOCK 4
#define BLOCK 256
#define ROWS_PER_BLOCK (ROWS_PER_WAVE * WAVES_PER_BLOCK)   // 8
#define TAIL_LANES (C4 - 6 * 64)  // 17

// One WAVE per TWO rows: all 28 loads (2x logits-row + 2x s-row) issued in
// one burst to double per-wave memory-level parallelism and halve the
// wave-slot turnover rate. R5/R6 established the kernel is memory-bound
// (VALU cuts moved total ~1 us); this targets issue burstiness.
// s[t,t]==1 exactly, so denom = sum_j s[t,j]*exp(l_j) (no j==t case).
// No max-subtraction (shift-invariant; N(0,1) logits can't overflow fp32).
__global__ __launch_bounds__(BLOCK) void seesaw_row_kernel(
    const float* __restrict__ logits,
    const float* __restrict__ s,
    const int*   __restrict__ targets,
    float*       __restrict__ row_loss)
{
    const int wave = threadIdx.x >> 6;
    const int lane = threadIdx.x & 63;
    const int b0 = blockIdx.x * ROWS_PER_BLOCK + wave * ROWS_PER_WAVE;
    const int b1 = b0 + 1;
    const int t0 = targets[b0];
    const int t1 = targets[b1];

    const float4* lrow0 = (const float4*)(logits + (size_t)b0 * C);
    const float4* lrow1 = (const float4*)(logits + (size_t)b1 * C);
    const float4* srow0 = (const float4*)(s + (size_t)t0 * C);
    const float4* srow1 = (const float4*)(s + (size_t)t1 * C);

    // target logits: broadcast loads, issued first
    const float lt0 = logits[(size_t)b0 * C + t0];
    const float lt1 = logits[(size_t)b1 * C + t1];

    // ---- issue all 28 row loads in one burst ----
    float4 la[7], sa[7], lb[7], sb[7];
    #pragma unroll
    for (int k = 0; k < 6; ++k) la[k] = lrow0[lane + 64 * k];
    #pragma unroll
    for (int k = 0; k < 6; ++k) lb[k] = lrow1[lane + 64 * k];
    #pragma unroll
    for (int k = 0; k < 6; ++k) sa[k] = srow0[lane + 64 * k];
    #pragma unroll
    for (int k = 0; k < 6; ++k) sb[k] = srow1[lane + 64 * k];
    const bool tail = lane < TAIL_LANES;
    la[6] = tail ? lrow0[lane + 384] : make_float4(0.f, 0.f, 0.f, 0.f);
    lb[6] = tail ? lrow1[lane + 384] : make_float4(0.f, 0.f, 0.f, 0.f);
    sa[6] = tail ? srow0[lane + 384] : make_float4(0.f, 0.f, 0.f, 0.f);
    sb[6] = tail ? srow1[lane + 384] : make_float4(0.f, 0.f, 0.f, 0.f);
    // (tail lanes: exp(0)*0 = 0 contribution: harmless)

    // ---- weighted-exp dot products (both rows) ----
    float p0 = 0.f, p1 = 0.f;
    #pragma unroll
    for (int k = 0; k < 7; ++k) {
        p0 += __expf(la[k].x) * sa[k].x;
        p0 += __expf(la[k].y) * sa[k].y;
        p0 += __expf(la[k].z) * sa[k].z;
        p0 += __expf(la[k].w) * sa[k].w;
        p1 += __expf(lb[k].x) * sb[k].x;
        p1 += __expf(lb[k].y) * sb[k].y;
        p1 += __expf(lb[k].z) * sb[k].z;
        p1 += __expf(lb[k].w) * sb[k].w;
    }
    #pragma unroll
    for (int off = 32; off > 0; off >>= 1) {
        p0 += __shfl_xor(p0, off, 64);
        p1 += __shfl_xor(p1, off, 64);
    }

    if (lane == 0) {
        const float sig0 = __expf(lt0) / (p0 + EPS);
        const float sig1 = __expf(lt1) / (p1 + EPS);
        row_loss[b0] = -logf(sig0 + EPS);
        row_loss[b1] = -logf(sig1 + EPS);
    }
}

// Deterministic final mean over B per-row losses (single block).
__global__ __launch_bounds__(1024) void seesaw_reduce_kernel(
    const float* __restrict__ in, float* __restrict__ out)
{
    const int tid = threadIdx.x;
    const float4* in4 = (const float4*)in;
    float acc = 0.f;
    #pragma unroll
    for (int i = tid; i < B / 4; i += 1024) {
        float4 v = in4[i];
        acc += (v.x + v.y) + (v.z + v.w);
    }
    #pragma unroll
    for (int off = 32; off > 0; off >>= 1)
        acc += __shfl_xor(acc, off, 64);
    __shared__ float sw[16];
    if ((tid & 63) == 0) sw[tid >> 6] = acc;
    __syncthreads();
    if (tid == 0) {
        float s0 = 0.f;
        #pragma unroll
        for (int w = 0; w < 16; ++w) s0 += sw[w];
        out[0] = s0 * (1.0f / B);
    }
}

extern "C" void kernel_launch(void* const* d_in, const int* in_sizes, int n_in,
                              void* d_out, int out_size, void* d_ws, size_t ws_size,
                              hipStream_t stream) {
    const float* logits  = (const float*)d_in[0];
    const float* s       = (const float*)d_in[1];
    const int*   targets = (const int*)d_in[2];
    float* out      = (float*)d_out;
    float* row_loss = (float*)d_ws;     // B floats = 64 KB scratch

    seesaw_row_kernel<<<B / ROWS_PER_BLOCK, BLOCK, 0, stream>>>(logits, s, targets, row_loss);
    seesaw_reduce_kernel<<<1, 1024, 0, stream>>>(row_loss, out);
}

// Round 8
// 161.494 us; speedup vs baseline: 1.0145x; 1.0145x over previous
//
#include <hip/hip_runtime.h>
#include <math.h>

#define EPS 1e-6f
#define C 1604
#define B 16384
#define C4 401                    // C/4 exact
#define ROWS_PER_BLOCK 4
#define BLOCK 256                 // 4 waves -> 4 rows
#define TAIL_LANES (C4 - 6 * 64)  // 17

// FINAL (R6 revert — best measured 161.6 us total; R7's 2-rows-per-wave
// variant regressed to 163.8).
// One WAVE per row. No LDS, no barriers, no atomics (R3/R4: per-block
// fence+atomic finalization cost ~150 us of coherence latency across 4096
// blocks on CDNA4 — two launches are far cheaper). No nontemporal loads
// (R3: nt demotes to a ~445 GB/s uncached path on gfx950).
// Algebra: s[t,t]==1 exactly (where(cond,ratio,ones) diagonal), so
//   denom[b] = sum_j s[t,j] * exp(l_j)   -- no j==t special case.
// No max-subtraction: ratio is shift-invariant; N(0,1) logits can't
// overflow fp32 exp. Target logit via one broadcast load.
__global__ __launch_bounds__(BLOCK) void seesaw_row_kernel(
    const float* __restrict__ logits,
    const float* __restrict__ s,
    const int*   __restrict__ targets,
    float*       __restrict__ row_loss)
{
    const int wave = threadIdx.x >> 6;
    const int lane = threadIdx.x & 63;
    const int b = blockIdx.x * ROWS_PER_BLOCK + wave;
    const int t = targets[b];

    const float4* lrow = (const float4*)(logits + (size_t)b * C);
    const float4* srow = (const float4*)(s + (size_t)t * C);

    // target logit: broadcast load, issued first
    const float lt = logits[(size_t)b * C + t];

    // ---- issue all 14 row loads ----
    float4 lv[7], sv[7];
    #pragma unroll
    for (int k = 0; k < 6; ++k) lv[k] = lrow[lane + 64 * k];
    #pragma unroll
    for (int k = 0; k < 6; ++k) sv[k] = srow[lane + 64 * k];
    const bool tail = lane < TAIL_LANES;
    lv[6] = tail ? lrow[lane + 384] : make_float4(0.f, 0.f, 0.f, 0.f);
    sv[6] = tail ? srow[lane + 384] : make_float4(0.f, 0.f, 0.f, 0.f);
    // (tail lanes: exp(0)*0 = 0 contribution: harmless)

    // ---- weighted-exp dot product ----
    float p = 0.f;
    #pragma unroll
    for (int k = 0; k < 7; ++k) {
        p += __expf(lv[k].x) * sv[k].x;
        p += __expf(lv[k].y) * sv[k].y;
        p += __expf(lv[k].z) * sv[k].z;
        p += __expf(lv[k].w) * sv[k].w;
    }
    #pragma unroll
    for (int off = 32; off > 0; off >>= 1)
        p += __shfl_xor(p, off, 64);

    if (lane == 0) {
        const float numt  = __expf(lt);
        const float sigma = numt / (p + EPS);
        row_loss[b] = -logf(sigma + EPS);
    }
}

// Deterministic final mean over B per-row losses (single block).
__global__ __launch_bounds__(1024) void seesaw_reduce_kernel(
    const float* __restrict__ in, float* __restrict__ out)
{
    const int tid = threadIdx.x;
    const float4* in4 = (const float4*)in;
    float acc = 0.f;
    #pragma unroll
    for (int i = tid; i < B / 4; i += 1024) {
        float4 v = in4[i];
        acc += (v.x + v.y) + (v.z + v.w);
    }
    #pragma unroll
    for (int off = 32; off > 0; off >>= 1)
        acc += __shfl_xor(acc, off, 64);
    __shared__ float sw[16];
    if ((tid & 63) == 0) sw[tid >> 6] = acc;
    __syncthreads();
    if (tid == 0) {
        float s0 = 0.f;
        #pragma unroll
        for (int w = 0; w < 16; ++w) s0 += sw[w];
        out[0] = s0 * (1.0f / B);
    }
}

extern "C" void kernel_launch(void* const* d_in, const int* in_sizes, int n_in,
                              void* d_out, int out_size, void* d_ws, size_t ws_size,
                              hipStream_t stream) {
    const float* logits  = (const float*)d_in[0];
    const float* s       = (const float*)d_in[1];
    const int*   targets = (const int*)d_in[2];
    float* out      = (float*)d_out;
    float* row_loss = (float*)d_ws;     // B floats = 64 KB scratch

    seesaw_row_kernel<<<B / ROWS_PER_BLOCK, BLOCK, 0, stream>>>(logits, s, targets, row_loss);
    seesaw_reduce_kernel<<<1, 1024, 0, stream>>>(row_loss, out);
}